// Round 6
// baseline (317.040 us; speedup 1.0000x reference)
//
#include <hip/hip_runtime.h>

#define U 256       // unknown node count
#define NN 1024     // total nodes
#define NROWS 32768 // B*T rows
#define LCAP 32     // capacity of "less" (earlier-unknown-neighbor) list per node
#define DUMMY 256   // padded index -> zero row of Ms

typedef __bf16 bf16_t;
typedef __bf16 bf16x4 __attribute__((ext_vector_type(4)));
typedef __bf16 bf16x8 __attribute__((ext_vector_type(8)));
typedef float f32x4 __attribute__((ext_vector_type(4)));
typedef unsigned short u16;
typedef unsigned short u16x8 __attribute__((ext_vector_type(8)));
typedef short s16x4 __attribute__((ext_vector_type(4)));

// async global->LDS DMA, 16 B per lane; dest is wave-uniform base + lane*16
__device__ __forceinline__ void gld16(const bf16_t* g, bf16_t* l) {
    __builtin_amdgcn_global_load_lds(
        (const __attribute__((address_space(1))) unsigned int*)(g),
        (__attribute__((address_space(3))) unsigned int*)(l), 16, 0, 0);
}

// ---------------------------------------------------------------------------
// K0: per unknown node k (one block each): deg, 1/deg, coef, less-list
// (ushort, DUMMY-padded). Block 0 also builds uflag + pmap + zeroes bvec.
// ---------------------------------------------------------------------------
__global__ __launch_bounds__(256) void k_struct(const float* __restrict__ A,
    const int* __restrict__ unknown, const float* __restrict__ maskp,
    float* __restrict__ invDeg, float* __restrict__ coef,
    int* __restrict__ lessCnt, u16* __restrict__ lessIdx,
    int* __restrict__ uflag, short* __restrict__ pmap, float* __restrict__ bvec)
{
    __shared__ int sunk[U];
    __shared__ float sdeg;
    __shared__ int scnt, sge;
    int t = threadIdx.x, k = blockIdx.x;
    sunk[t] = unknown[t];
    if (t == 0) { sdeg = 0.f; scnt = 0; sge = 0; }
    __syncthreads();
    int uk = sunk[k];
    float dsum = 0.f;
    for (int i = 0; i < NN / 256; ++i) {
        int n = t + 256 * i;
        float a = A[(size_t)uk * NN + n];
        if (a != 0.f) {
            dsum += a;
            int lo = 0, hi = U;
            while (lo < hi) { int mid = (lo + hi) >> 1; if (sunk[mid] < n) lo = mid + 1; else hi = mid; }
            if (lo < U && sunk[lo] == n) {
                if (lo < k) {
                    int id = atomicAdd(&scnt, 1);
                    if (id < LCAP) lessIdx[k * LCAP + id] = (u16)lo;
                } else {
                    atomicAdd(&sge, 1);
                }
            }
        }
    }
    atomicAdd(&sdeg, dsum);
    __syncthreads();
    int c0 = min(scnt, LCAP);
    if (t >= c0 && t < LCAP) lessIdx[k * LCAP + t] = DUMMY;   // pad
    if (t == 0) {
        float inv = 1.f / sdeg;
        invDeg[k] = inv;
        coef[k] = (float)sge * maskp[0] * inv;
        lessCnt[k] = c0;
    }
    if (k == 0) {
        for (int i = 0; i < NN / 256; ++i) { uflag[t + 256 * i] = 0; pmap[t + 256 * i] = -1; }
        bvec[t] = 0.f;                      // accumulated by k_mbuild atomics
        __syncthreads();
        uflag[sunk[t]] = 1;
        pmap[sunk[t]] = (short)t;
    }
}

// ---------------------------------------------------------------------------
// K1: levels computed REDUNDANTLY per block (8 concurrent blocks) +
// level-parallel forward substitution for M = (I - Ltilde)^-1.
// Writes MT[col*U + k] (f32, col-major) and accumulates bvec = M * coef.
// ---------------------------------------------------------------------------
__global__ __launch_bounds__(256) void k_mbuild(const int* __restrict__ lessCnt,
    const u16* __restrict__ lessIdx, const float* __restrict__ invDeg,
    const float* __restrict__ coef, float* __restrict__ MT, float* __restrict__ bvec)
{
    __shared__ u16 sIdx[U * LCAP];
    __shared__ int slvl[U];
    __shared__ int hist[U];
    __shared__ int changed;
    __shared__ int snl;
    __shared__ float Ms[(U + 1) * 32];    // row U = zeros (dummy target)
    __shared__ float sInv[U];
    __shared__ u16 sOrd[U];
    __shared__ unsigned char sCnt[U];
    __shared__ int sLs[U + 1];
    __shared__ float scf[U];
    int t = threadIdx.x;
    for (int i = t; i < U * LCAP / 2; i += 256) ((unsigned int*)sIdx)[i] = ((const unsigned int*)lessIdx)[i];
    int myCnt = lessCnt[t];
    sCnt[t] = (unsigned char)myCnt;
    sInv[t] = invDeg[t];
    scf[t] = coef[t];
    slvl[t] = 0; hist[t] = 0;
    __syncthreads();
    // Jacobi to level fixpoint
    for (int iter = 0; iter < U; ++iter) {
        if (t == 0) changed = 0;
        __syncthreads();
        int nl = 0;
        for (int i = 0; i < myCnt; ++i) nl = max(nl, slvl[sIdx[t * LCAP + i]] + 1);
        if (nl > slvl[t]) { slvl[t] = nl; changed = 1; }
        __syncthreads();
        if (!changed) break;   // uniform
    }
    int L = slvl[t];
    atomicAdd(&hist[L], 1);
    __syncthreads();
    if (t == 0) {
        int acc = 0, lastl = 0;
        for (int l = 0; l < U; ++l) {
            int h = hist[l];
            hist[l] = acc;          // hist becomes start offset
            acc += h;
            if (h > 0) lastl = l;
        }
        snl = lastl + 1;
    }
    __syncthreads();
    sLs[t] = hist[t];               // save starts BEFORE scatter clobbers
    if (t == 0) sLs[U] = U;
    if (t < 32) Ms[U * 32 + t] = 0.f;
    __syncthreads();
    int pos = atomicAdd(&hist[L], 1);
    sOrd[pos] = (u16)t;
    int nlv = snl;
    __syncthreads();
    // level-parallel forward substitution
    int g = t >> 5, c = t & 31;
    int col = blockIdx.x * 32 + c;
    for (int lev = 0; lev < nlv; ++lev) {
        int s = sLs[lev], e = sLs[lev + 1];
        for (int base = s + g; base < e; base += 8) {
            int k = sOrd[base];
            int cnt = sCnt[k];
            const u16* ip = &sIdx[k * LCAP];
            float sum = 0.f;
            for (int b = 0; b < cnt; b += 8) {
                u16x8 jv = *(const u16x8*)(ip + b);   // one ds_read_b128
                float v0 = Ms[jv[0] * 32 + c];
                float v1 = Ms[jv[1] * 32 + c];
                float v2 = Ms[jv[2] * 32 + c];
                float v3 = Ms[jv[3] * 32 + c];
                float v4 = Ms[jv[4] * 32 + c];
                float v5 = Ms[jv[5] * 32 + c];
                float v6 = Ms[jv[6] * 32 + c];
                float v7 = Ms[jv[7] * 32 + c];
                sum += ((v0 + v1) + (v2 + v3)) + ((v4 + v5) + (v6 + v7));
            }
            float m = (k == col ? 1.f : 0.f) + sInv[k] * sum;
            Ms[k * 32 + c] = m;
            MT[(size_t)col * U + k] = m;   // col-major (M^T) for k_wbuild
        }
        __syncthreads();   // level boundary
    }
    // bvec partial: bvec[k] += sum_{c in this block} M[k][c]*coef[c]
    float s = 0.f;
    #pragma unroll 8
    for (int j = 0; j < 32; ++j) {
        int cl = (j + (t & 31)) & 31;
        s += Ms[t * 32 + cl] * scf[blockIdx.x * 32 + cl];
    }
    atomicAdd(&bvec[t], s);
}

// ---------------------------------------------------------------------------
// K2: W[u][d] (bf16) from A, M (f32 compute).
// ---------------------------------------------------------------------------
__global__ __launch_bounds__(256) void k_wbuild(const float* __restrict__ A,
    const int* __restrict__ unknown, const float* __restrict__ invDeg,
    const int* __restrict__ uflag, const float* __restrict__ MT,
    bf16_t* __restrict__ Wb)
{
    int t = threadIdx.x, d = blockIdx.x;
    if (uflag[d]) { Wb[(size_t)t * NN + d] = (bf16_t)0.f; return; }  // block-uniform
    __shared__ int nnz;
    __shared__ int cs[64];
    __shared__ float vsv[64];
    if (t == 0) nnz = 0;
    __syncthreads();
    float a = A[(size_t)unknown[t] * NN + d];
    if (a != 0.f) {
        int id = atomicAdd(&nnz, 1);
        if (id < 64) { cs[id] = t; vsv[id] = a * invDeg[t]; }
    }
    __syncthreads();
    int n = min(nnz, 64);
    float s = 0.f;
    for (int i = 0; i < n; ++i)
        s += MT[(size_t)cs[i] * U + t] * vsv[i];   // coalesced over t; zero above diag
    Wb[(size_t)t * NN + d] = (bf16_t)s;
}

// ---------------------------------------------------------------------------
// K3 v6: m97-structure GEMM. V-staging via global_load_lds (async DMA, no
// VGPR roundtrip) with PRE-SWIZZLED SOURCE: lane fetches global col-slot
// (t&7)^((t>>3)&7) so the linear LDS placement lands XOR-swizzled; ds_read
// applies the same XOR -> <=2-way banks. X-staging stays reg-staged (f32->
// bf16 cvt) into padded Xl. Single-buffered, 2 barriers/chunk; LDS ~45 KB ->
// 3 blocks/CU capacity, grid 512 -> 2 resident/CU for drain overlap.
// ---------------------------------------------------------------------------
#define RT 64
#define BK 64
#define LDX 72      // X tile: 64 + 8 bf16 pad (reg-staged, padding OK)
#define URS 257     // Ures row stride (f32)

__global__ __launch_bounds__(512, 6) void k_main(const float* __restrict__ x,
    const short* __restrict__ pmap, const bf16_t* __restrict__ Wb,
    const float* __restrict__ bvec, float* __restrict__ out)
{
    __shared__ __align__(16) char smem[41984];  // Xl 9216 + Vl 32768; Ures 32896 overlays
    __shared__ float sb[U];
    __shared__ short spm[NN];
    bf16_t* Xl = (bf16_t*)smem;
    bf16_t* Vl = (bf16_t*)(smem + 9216);        // linear [256][64] bf16, swizzled content
    float* Ures = (float*)smem;
    int t = threadIdx.x;
    int w = t >> 6, l = t & 63;
    int m = l & 15, q = l >> 4;
    int rg = w >> 2, cg = w & 3;
    size_t row0 = (size_t)blockIdx.x * RT;
    if (t < U) sb[t] = bvec[t];
    spm[t] = pmap[t];
    spm[t + 512] = pmap[t + 512];
    f32x4 acc[2][4] = {};
    int uv = t >> 3;                                  // V row within 64-row group
    int du2 = (((t & 7) ^ ((t >> 3) & 7)) << 3);      // swizzled global col (elems)
    int vslot = uv * 64 + (t & 7) * 8;                // linear LDS elem slot (== base + lane*16B)
    int mx8 = (m & 7) << 3;                           // read-side XOR (elems)

    float4 xr[2];
#define LOADX(DB) do { \
    _Pragma("unroll") \
    for (int ii = 0; ii < 2; ++ii) { \
        int flat = t + ii * 512; \
        int r = flat >> 4, c4 = (flat & 15) * 4; \
        xr[ii] = *(const float4*)(x + (row0 + r) * NN + (DB) + c4); \
    } \
} while (0)

    LOADX(0);
    for (int db = 0; db < NN; db += BK) {
        __syncthreads();   // prev chunk's LDS reads done (covers sb/spm on iter 0)
        // async V stage: 4x global_load_lds_dwordx4, pre-swizzled source
        #pragma unroll
        for (int i = 0; i < 4; ++i)
            gld16(Wb + (size_t)(uv + 64 * i) * NN + db + du2, Vl + vslot + i * 4096);
        // X stage from prefetched regs (compiler waits only the 2 xr loads)
        #pragma unroll
        for (int ii = 0; ii < 2; ++ii) {
            int flat = t + ii * 512;
            int r = flat >> 4, c4 = (flat & 15) * 4;
            float4 v = xr[ii];
            bf16x4 hv = { (bf16_t)v.x, (bf16_t)v.y, (bf16_t)v.z, (bf16_t)v.w };
            *(bf16x4*)(&Xl[r * LDX + c4]) = hv;
        }
        if (db + BK < NN) LOADX(db + BK);   // prefetch next x chunk
        __syncthreads();   // drains gloads (V ready) + xr-next (early, harmless)
        #pragma unroll
        for (int s = 0; s < 2; ++s) {
            bf16x8 af[2];
            #pragma unroll
            for (int R = 0; R < 2; ++R)
                af[R] = *(bf16x8*)(&Xl[(rg * 32 + R * 16 + m) * LDX + s * 32 + q * 8]);
            #pragma unroll
            for (int T = 0; T < 4; ++T) {
                int vrow = (cg * 4 + T) * 16 + m;
                bf16x8 bfr = *(bf16x8*)(&Vl[vrow * 64 + ((s * 32 + q * 8) ^ mx8)]);
                #pragma unroll
                for (int R = 0; R < 2; ++R)
                    acc[R][T] = __builtin_amdgcn_mfma_f32_16x16x32_bf16(af[R], bfr, acc[R][T], 0, 0, 0);
            }
        }
    }
#undef LOADX
    // epilogue: two 32-row halves; waves with rg==h stage acc (+bias) into Ures
    #pragma unroll
    for (int h = 0; h < 2; ++h) {
        __syncthreads();   // all Vl/Xl (or previous half's Ures) reads done
        if (rg == h) {     // wave-uniform branch
            #pragma unroll
            for (int R = 0; R < 2; ++R) {
                #pragma unroll
                for (int T = 0; T < 4; ++T) {
                    int u = (cg * 4 + T) * 16 + m;
                    float bb = sb[u];
                    #pragma unroll
                    for (int i = 0; i < 4; ++i)
                        Ures[(R * 16 + q * 4 + i) * URS + u] = acc[R][T][i] + bb;
                }
            }
        }
        __syncthreads();
        // merged single-pass write: re-read x (L3-warm), substitute unknown cols
        int c4i = t & 255, rh = t >> 8;
        s16x4 pm = *(const s16x4*)(&spm[c4i * 4]);
        #pragma unroll 4
        for (int it = 0; it < 16; ++it) {
            int lr = 2 * it + rh;   // local row 0..31
            float4 v = *(const float4*)(x + (row0 + h * 32 + lr) * NN + c4i * 4);
            if (pm[0] >= 0) v.x = Ures[lr * URS + pm[0]];
            if (pm[1] >= 0) v.y = Ures[lr * URS + pm[1]];
            if (pm[2] >= 0) v.z = Ures[lr * URS + pm[2]];
            if (pm[3] >= 0) v.w = Ures[lr * URS + pm[3]];
            *(float4*)(out + (row0 + h * 32 + lr) * NN + c4i * 4) = v;
        }
    }
}

// ---------------------------------------------------------------------------
extern "C" void kernel_launch(void* const* d_in, const int* in_sizes, int n_in,
                              void* d_out, int out_size, void* d_ws, size_t ws_size,
                              hipStream_t stream)
{
    const float* x       = (const float*)d_in[0];
    const float* A       = (const float*)d_in[1];
    const int*   unknown = (const int*)d_in[2];
    const float* maskp   = (const float*)d_in[3];
    float* out = (float*)d_out;

    char* ws = (char*)d_ws;
    float*  MT      = (float*)(ws + 0);        // 262144 B
    bf16_t* Wb      = (bf16_t*)(ws + 262144);  // 524288 B
    float*  invDeg  = (float*)(ws + 786432);   // 1024 B
    float*  coef    = (float*)(ws + 787456);   // 1024 B
    float*  bvec    = (float*)(ws + 788480);   // 1024 B
    int*    lessCnt = (int*)(ws + 789504);     // 1024 B
    u16*    lessIdx = (u16*)(ws + 790528);     // 16384 B
    int*    uflag   = (int*)(ws + 806912);     // 4096 B
    short*  pmap    = (short*)(ws + 811008);   // 2048 B

    hipLaunchKernelGGL(k_struct, dim3(U), dim3(256), 0, stream,
                       A, unknown, maskp, invDeg, coef, lessCnt, lessIdx, uflag, pmap, bvec);
    hipLaunchKernelGGL(k_mbuild, dim3(8), dim3(256), 0, stream,
                       lessCnt, lessIdx, invDeg, coef, MT, bvec);
    hipLaunchKernelGGL(k_wbuild, dim3(NN), dim3(256), 0, stream,
                       A, unknown, invDeg, uflag, MT, Wb);
    hipLaunchKernelGGL(k_main, dim3(NROWS / RT), dim3(512), 0, stream,
                       x, pmap, Wb, bvec, out);
}